// Round 13
// baseline (63.360 us; speedup 1.0000x reference)
//
#include <hip/hip_runtime.h>
#include <math.h>

#define B_    8
#define N_    1024
#define FIN   512
#define FOUT  256
#define ALPHA 0.2f
#define EPSV  1e-5f

typedef __attribute__((ext_vector_type(8))) short bf16x8;
typedef __attribute__((ext_vector_type(4))) float f32x4;

__device__ __forceinline__ short f2bf(float x) {          // RNE
    unsigned u = __builtin_bit_cast(unsigned, x);
    u = (u + 0x7FFFu + ((u >> 16) & 1u)) >> 16;
    return (short)u;
}
__device__ __forceinline__ short f2bf_fast(float x) {     // round-half-up (P path)
    unsigned u = __builtin_bit_cast(unsigned, x);
    return (short)((u + 0x8000u) >> 16);
}
__device__ __forceinline__ float bf2f(short s) {
    return __builtin_bit_cast(float, ((unsigned)(unsigned short)s) << 16);
}
__device__ __forceinline__ float gelu_exact(float x) {
    return 0.5f * x * (1.0f + erff(x * 0.70710678118654752f));
}

// Fragment-linear chunks (1 KB = 64 lanes x 16B):
//   Apack[b][m16][kt][l][u8] : lane l=(lq*16+lr) holds P[m16*16+lr][kt*32+lq*8+u]
//   Bpack[b][n16][kt][l][u8] : lane l=(lq*16+lr) holds Wh[kt*32+lq*8+u][n16*16+lr]
// Bit matrix (A-frag byte order): byte bits[row*128 + lq*32 + kt] = adj bits
//   for j = kt*32 + lq*8 + u (u = bit 0..7).

// ---------------------------------------------------------------------------
// k_prep: W (512x256 fp32 row-major) -> WT (256x512 bf16, [col][k]).
// ---------------------------------------------------------------------------
__global__ __launch_bounds__(256) void k_prep(const float* __restrict__ W,
                                              short* __restrict__ WT) {
    int id  = blockIdx.x * 256 + threadIdx.x;
    int col = id >> 7;
    int k4  = (id & 127) * 4;
    short4 v;
    v.x = f2bf(W[(k4 + 0) * FOUT + col]);
    v.y = f2bf(W[(k4 + 1) * FOUT + col]);
    v.z = f2bf(W[(k4 + 2) * FOUT + col]);
    v.w = f2bf(W[(k4 + 3) * FOUT + col]);
    *(short4*)(WT + (long)col * FIN + k4) = v;
}

// ---------------------------------------------------------------------------
// k_bits: adj (read once, coalesced 2KB/wave) -> bitmask in A-frag byte
// order. One wave per row. Grid = 2048. (HBM-roofline: ~6 us)
// ---------------------------------------------------------------------------
__global__ __launch_bounds__(256) void k_bits(const float* __restrict__ adj,
                                              unsigned char* __restrict__ bits) {
    const int tid = threadIdx.x;
    const int w   = tid >> 6, l = tid & 63;
    const long gr = (long)blockIdx.x * 4 + w;          // global row 0..8191
    const float* __restrict__ arow = adj + gr * N_;

    unsigned b0 = 0, b1 = 0;
    {
        float4 x0 = *(const float4*)(arow + l * 8);
        float4 x1 = *(const float4*)(arow + l * 8 + 4);
        float aa[8] = {x0.x, x0.y, x0.z, x0.w, x1.x, x1.y, x1.z, x1.w};
        #pragma unroll
        for (int u = 0; u < 8; ++u) b0 |= (aa[u] > 0.f ? 1u : 0u) << u;
        float4 y0 = *(const float4*)(arow + 512 + l * 8);
        float4 y1 = *(const float4*)(arow + 512 + l * 8 + 4);
        float bb[8] = {y0.x, y0.y, y0.z, y0.w, y1.x, y1.y, y1.z, y1.w};
        #pragma unroll
        for (int u = 0; u < 8; ++u) b1 |= (bb[u] > 0.f ? 1u : 0u) << u;
    }
    unsigned out2 = 0;
    #pragma unroll
    for (int k = 0; k < 2; ++k) {
        int o   = 2 * l + k;
        int lqd = o >> 5, ktd = o & 31;
        int src = ((ktd & 15) << 2) | lqd;
        unsigned v0 = __shfl(b0, src, 64);
        unsigned v1 = __shfl(b1, src, 64);
        unsigned v  = (ktd & 16) ? v1 : v0;
        out2 |= (v & 0xFFu) << (8 * k);
    }
    *(unsigned short*)(bits + gr * 128 + l * 2) = (unsigned short)out2;
}

// ---------------------------------------------------------------------------
// k_wh: Wh = h @ W via bf16 MFMA; writes Bpack (fragment-linear) + F1/F2.
// Block = 256 thr / 4 waves; 16 node-rows; grid = 512.
// ---------------------------------------------------------------------------
__global__ __launch_bounds__(256) void k_wh(const float* __restrict__ h,
                                            const short* __restrict__ WT,
                                            const float* __restrict__ a,
                                            short* __restrict__ Bpack,
                                            float* __restrict__ F1,
                                            float* __restrict__ F2) {
    const int tid = threadIdx.x;
    const int w   = tid >> 6, l = tid & 63;
    const int lr  = l & 15, lq = l >> 4;
    const long row0 = (long)blockIdx.x * 16;
    const int colbase = w * 64;

    __shared__ float r1[4][16], r2[4][16];

    f32x4 acc[4] = {};
    const float* hrow = h + (row0 + lr) * FIN + lq * 8;

    #pragma unroll
    for (int k0 = 0; k0 < FIN; k0 += 32) {
        float4 v0 = *(const float4*)(hrow + k0);
        float4 v1 = *(const float4*)(hrow + k0 + 4);
        bf16x8 af;
        af[0] = f2bf(v0.x); af[1] = f2bf(v0.y); af[2] = f2bf(v0.z); af[3] = f2bf(v0.w);
        af[4] = f2bf(v1.x); af[5] = f2bf(v1.y); af[6] = f2bf(v1.z); af[7] = f2bf(v1.w);
        #pragma unroll
        for (int c = 0; c < 4; ++c) {
            const short* bp = WT + (long)(colbase + c * 16 + lr) * FIN + k0 + lq * 8;
            bf16x8 bf = *(const bf16x8*)bp;
            acc[c] = __builtin_amdgcn_mfma_f32_16x16x32_bf16(af, bf, acc[c], 0, 0, 0);
        }
    }

    const int b   = (int)(row0 >> 10);
    const int il0 = (int)(row0 & 1023);
    const int kt  = il0 >> 5;
    const int h16 = (il0 >> 4) & 1;
    const int lp  = (h16 * 2 + (lq >> 1)) * 16 + lr;
    const int u0  = (lq & 1) * 4;
    short* bpo = Bpack + ((long)b * 16 * 32) * 512;
    #pragma unroll
    for (int c = 0; c < 4; ++c) {
        short4 s;
        s.x = f2bf(acc[c][0]); s.y = f2bf(acc[c][1]);
        s.z = f2bf(acc[c][2]); s.w = f2bf(acc[c][3]);
        int n16 = w * 4 + c;
        *(short4*)(bpo + ((long)(n16 * 32 + kt)) * 512 + lp * 8 + u0) = s;
    }

    float p1[4] = {0.f, 0.f, 0.f, 0.f}, p2[4] = {0.f, 0.f, 0.f, 0.f};
    #pragma unroll
    for (int c = 0; c < 4; ++c) {
        int col = colbase + c * 16 + lr;
        float a1v = a[col], a2v = a[FOUT + col];
        #pragma unroll
        for (int j = 0; j < 4; ++j) { p1[j] += acc[c][j] * a1v; p2[j] += acc[c][j] * a2v; }
    }
    #pragma unroll
    for (int off = 1; off < 16; off <<= 1) {
        #pragma unroll
        for (int j = 0; j < 4; ++j) {
            p1[j] += __shfl_xor(p1[j], off, 64);
            p2[j] += __shfl_xor(p2[j], off, 64);
        }
    }
    if (lr == 0) {
        #pragma unroll
        for (int j = 0; j < 4; ++j) { r1[w][lq * 4 + j] = p1[j]; r2[w][lq * 4 + j] = p2[j]; }
    }
    __syncthreads();
    if (tid < 16) {
        F1[row0 + tid] = r1[0][tid] + r1[1][tid] + r1[2][tid] + r1[3][tid];
        F2[row0 + tid] = r2[0][tid] + r2[1][tid] + r2[2][tid] + r2[3][tid];
    }
}

// ---------------------------------------------------------------------------
// k_pgen v3 (FIXED: apb base no longer double-adds l*8): Apack = bit ?
// exp(leaky(f1+f2)) : 0 (bf16, m=0 softmax), from the 1 MB bitmask (L2) +
// LDS f2. Pure streaming writes (1KB/wave). Block = 256 thr / 4 waves;
// grid = (8, 64, 2): z = kt-half, wave w does kt = z*16 + w*4 .. +3.
// ---------------------------------------------------------------------------
__global__ __launch_bounds__(256) void k_pgen(const unsigned char* __restrict__ bits,
                                              const float* __restrict__ F1,
                                              const float* __restrict__ F2,
                                              short* __restrict__ Apack) {
    const int tid = threadIdx.x;
    const int b   = blockIdx.x;
    const int m16 = blockIdx.y;
    const int z   = blockIdx.z;
    const int w   = tid >> 6, l = tid & 63;
    const int lr  = l & 15, lq = l >> 4;
    const int i0  = m16 * 16;

    __shared__ float f2s[N_];
    { int j = tid * 4; *(float4*)&f2s[j] = *(const float4*)(F2 + b * N_ + j); }
    __syncthreads();

    const float f1 = F1[b * N_ + i0 + lr];
    const int kt0 = z * 16 + w * 4;
    // 4 mask bytes (kt0..kt0+3) for (row=i0+lr, lq): one aligned u32
    const unsigned bw = *(const unsigned*)(bits + ((long)(b * N_ + i0 + lr)) * 128 + lq * 32 + kt0);
    short* __restrict__ apb = Apack + (((long)b * 64 + m16) * 32) * 512;   // chunk base ONLY

    #pragma unroll
    for (int it = 0; it < 4; ++it) {
        const int kt = kt0 + it;
        const unsigned byte = (bw >> (it * 8)) & 0xFFu;
        float f2k[8];
        *(float4*)&f2k[0] = *(const float4*)&f2s[kt * 32 + lq * 8];
        *(float4*)&f2k[4] = *(const float4*)&f2s[kt * 32 + lq * 8 + 4];
        bf16x8 pv;
        #pragma unroll
        for (int u = 0; u < 8; ++u) {
            float x  = f1 + f2k[u];
            float tt = fmaxf(x, ALPHA * x);
            float e  = ((byte >> u) & 1u) ? __expf(tt) : 0.f;
            pv[u] = f2bf_fast(e);
        }
        *(bf16x8*)(apb + (long)kt * 512 + l * 8) = pv;   // 1KB/wave contiguous
    }
}

// ---------------------------------------------------------------------------
// k_pv v5: pure GEMM h_prime = (Apack @ Bpack)/l + LN + GELU. R8 geometry
// (best-measured PV) + DEPTH-2 register prefetch. Block = 1024 thr / 16
// waves = 2 rg x 4 cw x 2 kg; wave = 16 rows x 64 cols x K=512. Grid =
// (8, 32); blockIdx.x = batch pins Bpack slab to one XCD L2. l summed from
// A-frags in-loop (free VALU). __launch_bounds__(1024,4) -> VGPR<=128,
// 4 waves/SIMD.
// ---------------------------------------------------------------------------
__global__ __launch_bounds__(1024, 4) void k_pv(const short* __restrict__ Apack,
                                                const short* __restrict__ Bpack,
                                                const float* __restrict__ gamma,
                                                const float* __restrict__ beta,
                                                float* __restrict__ out) {
    const int tid = threadIdx.x;
    const int b   = blockIdx.x;
    const int w   = tid >> 6, l = tid & 63;
    const int lr  = l & 15, lq = l >> 4;
    const int cw  = w & 3;          // col wave: cols cw*64..+63
    const int rg  = (w >> 2) & 1;   // row group
    const int kg  = w >> 3;         // K half
    const int m16 = blockIdx.y * 2 + rg;

    __shared__ float sc[2][4][16][68];            // cross-kg partials
    __shared__ float lnp1[2][4][16], lnp2[2][4][16];
    __shared__ float lsumS[2][2][16];             // [rg][kg][row]

    const short* ap = Apack + (((long)b * 64 + m16) * 32 + kg * 16) * 512 + l * 8;
    const short* bp = Bpack + (((long)b * 16 + cw * 4) * 32 + kg * 16) * 512 + l * 8;

    f32x4 acc[4] = {};
    float ls = 0.f;

    // depth-2 prefetch buffers
    bf16x8 aP[2], bP[2][4];
    #pragma unroll
    for (int d = 0; d < 2; ++d) {
        aP[d] = *(const bf16x8*)(ap + d * 512);
        #pragma unroll
        for (int cf = 0; cf < 4; ++cf)
            bP[d][cf] = *(const bf16x8*)(bp + (long)(cf * 32 + d) * 512);
    }

    #pragma unroll
    for (int t = 0; t < 16; ++t) {
        const int cur = t & 1;                    // compile-time after unroll
        bf16x8 aC = aP[cur];
        bf16x8 b0 = bP[cur][0], b1 = bP[cur][1], b2 = bP[cur][2], b3 = bP[cur][3];
        if (t < 14) {
            aP[cur] = *(const bf16x8*)(ap + (t + 2) * 512);
            #pragma unroll
            for (int cf = 0; cf < 4; ++cf)
                bP[cur][cf] = *(const bf16x8*)(bp + (long)(cf * 32 + t + 2) * 512);
        }
        #pragma unroll
        for (int u = 0; u < 8; ++u) ls += bf2f(aC[u]);   // l partial (VALU)
        acc[0] = __builtin_amdgcn_mfma_f32_16x16x32_bf16(aC, b0, acc[0], 0, 0, 0);
        acc[1] = __builtin_amdgcn_mfma_f32_16x16x32_bf16(aC, b1, acc[1], 0, 0, 0);
        acc[2] = __builtin_amdgcn_mfma_f32_16x16x32_bf16(aC, b2, acc[2], 0, 0, 0);
        acc[3] = __builtin_amdgcn_mfma_f32_16x16x32_bf16(aC, b3, acc[3], 0, 0, 0);
    }

    // row sums for this kg half
    ls += __shfl_xor(ls, 16, 64);
    ls += __shfl_xor(ls, 32, 64);
    if (cw == 0 && lq == 0) lsumS[rg][kg][lr] = ls;

    // cross-kg reduce: kg=1 waves park partials
    if (kg == 1) {
        #pragma unroll
        for (int cf = 0; cf < 4; ++cf)
            #pragma unroll
            for (int jj = 0; jj < 4; ++jj)
                sc[rg][cw][lq * 4 + jj][cf * 16 + lr] = acc[cf][jj];
    }
    __syncthreads();

    if (kg == 0) {
        #pragma unroll
        for (int cf = 0; cf < 4; ++cf)
            #pragma unroll
            for (int jj = 0; jj < 4; ++jj)
                acc[cf][jj] += sc[rg][cw][lq * 4 + jj][cf * 16 + lr];

        float il[4];
        #pragma unroll
        for (int jj = 0; jj < 4; ++jj) {
            float r = lsumS[rg][0][lq * 4 + jj] + lsumS[rg][1][lq * 4 + jj];
            il[jj] = (r > 0.f) ? 1.0f / r : 0.f;
        }
        float s1[4] = {0.f,0.f,0.f,0.f}, s2[4] = {0.f,0.f,0.f,0.f};
        #pragma unroll
        for (int cf = 0; cf < 4; ++cf)
            #pragma unroll
            for (int jj = 0; jj < 4; ++jj) {
                float v = acc[cf][jj] * il[jj];
                acc[cf][jj] = v;
                s1[jj] += v;
                s2[jj] += v * v;
            }
        #pragma unroll
        for (int off = 1; off < 16; off <<= 1)
            #pragma unroll
            for (int jj = 0; jj < 4; ++jj) {
                s1[jj] += __shfl_xor(s1[jj], off, 64);
                s2[jj] += __shfl_xor(s2[jj], off, 64);
            }
        if (lr == 0) {
            #pragma unroll
            for (int jj = 0; jj < 4; ++jj) {
                lnp1[rg][cw][lq * 4 + jj] = s1[jj];
                lnp2[rg][cw][lq * 4 + jj] = s2[jj];
            }
        }
    }
    __syncthreads();

    if (kg == 0) {
        #pragma unroll
        for (int jj = 0; jj < 4; ++jj) {
            int row = lq * 4 + jj;
            float t1 = lnp1[rg][0][row] + lnp1[rg][1][row] + lnp1[rg][2][row] + lnp1[rg][3][row];
            float t2 = lnp2[rg][0][row] + lnp2[rg][1][row] + lnp2[rg][2][row] + lnp2[rg][3][row];
            float mu   = t1 * (1.0f / FOUT);
            float rstd = rsqrtf(t2 * (1.0f / FOUT) - mu * mu + EPSV);
            #pragma unroll
            for (int cf = 0; cf < 4; ++cf) {
                int col = cw * 64 + cf * 16 + lr;
                out[((long)b * N_ + m16 * 16 + row) * FOUT + col] =
                    gelu_exact((acc[cf][jj] - mu) * rstd * gamma[col] + beta[col]);
            }
        }
    }
}

extern "C" void kernel_launch(void* const* d_in, const int* in_sizes, int n_in,
                              void* d_out, int out_size, void* d_ws, size_t ws_size,
                              hipStream_t stream) {
    const float* h     = (const float*)d_in[0];
    const float* adj   = (const float*)d_in[1];
    // d_in[2]=q_type, d_in[3]=pos : unused scalars
    const float* W     = (const float*)d_in[4];
    const float* a     = (const float*)d_in[5];
    const float* gamma = (const float*)d_in[6];
    const float* beta  = (const float*)d_in[7];
    float* out = (float*)d_out;

    // workspace layout (~21.6 MB)
    short* Apack = (short*)d_ws;                          // 8*64*32*512 = 16 MB
    short* Bpack = Apack + (size_t)B_ * 64 * 32 * 512;    // 4 MB
    short* WT    = Bpack + (size_t)B_ * 16 * 32 * 512;    // 256 KB
    float* F1    = (float*)(WT + (size_t)FOUT * FIN);     // 32 KB
    float* F2    = F1 + (size_t)B_ * N_;                  // 32 KB
    unsigned char* bits = (unsigned char*)(F2 + (size_t)B_ * N_);  // 1 MB

    k_prep<<<dim3(128), 256, 0, stream>>>(W, WT);
    k_bits<<<dim3(B_ * N_ / 4), 256, 0, stream>>>(adj, bits);
    k_wh  <<<dim3(B_ * N_ / 16), 256, 0, stream>>>(h, WT, a, Bpack, F1, F2);
    k_pgen<<<dim3(B_, N_ / 16, 2), 256, 0, stream>>>(bits, F1, F2, Apack);
    k_pv  <<<dim3(B_, N_ / 32), 1024, 0, stream>>>(Apack, Bpack, gamma, beta, out);
}